// Round 6
// baseline (962.998 us; speedup 1.0000x reference)
//
#include <hip/hip_runtime.h>

#define N_NODES 20000
#define N_EDGES 320000
#define R_RUNS 10
#define HID 64
#define NG 128
#define NC 10
#define NL 4
#define MROWS (R_RUNS * N_NODES)   // 200000
#define BN_EPS 1e-5f
#define NCOPY 16                   // stats copies per buffer

typedef __bf16 bf16;
typedef __attribute__((ext_vector_type(8))) __bf16 bf16x8;
typedef __attribute__((ext_vector_type(4))) float f32x4;
typedef unsigned int uint32;

// ---------------- workspace layout (bytes)
// Feature layout [n][r][f] (row = n*10+r): agg gathers a neighbor's 10 runs
// from one contiguous 1280B span; pool's r-reduction is contiguous.
constexpr size_t OFF_FLAGS   = 0;          // int[4] counters, pad 256
constexpr size_t OFF_CURSOR  = 256;        // int[20001] -> pad 80384
constexpr size_t OFF_STATS   = 80384;      // f32[8 bufs][16 copies][128] = 65536
constexpr size_t OFF_POOLED5 = 145920;     // f32[5][128][64] = 163840
constexpr size_t ZERO_BYTES  = 309760;
constexpr size_t OFF_ROWST   = 309760;     // int[20001] -> pad 389888
constexpr size_t OFF_COL     = 389888;     // int[320000] -> 1669888
constexpr size_t OFF_PARAMS  = 1669888;    // bf16[37554] -> pad 1745152
constexpr size_t OFF_XB      = 1745152;    // bf16[1280000] -> 4305152
constexpr size_t OFF_H       = 4305152;    // 25,600,000
constexpr size_t OFF_Z       = 29905152;   // 25,600,000 -> end 55,505,152

// params block element offsets (w1/w2 stored PRE-SWIZZLED in B-fragment order)
#define PW1  0
#define PB1  16384
#define PG1  16640
#define PBB1 16896
#define PW2  17152
#define PB2  33536
#define PG2  33792
#define PBB2 34048
#define PFW  34304
#define PFB  37504
#define PTOT 37554
#define CVT_TOT (1280000 + PTOT)

// ---------------- runtime dtype detection (validated R4/R5) ----------------
__global__ void detect_kernel(const unsigned short* __restrict__ xu,
                              const unsigned int* __restrict__ mw,
                              int* __restrict__ cnts) {
    int tid = blockIdx.x * 256 + threadIdx.x;   // 16384 threads
    int insane = 0, lowp = 0, f32w = 0, gt1 = 0;
    for (int i = tid; i < 4096; i += 16384) {
        unsigned int u = xu[2 * i];
        if (((u >> 7) & 0xFFu) >= 0x90u) insane++;
    }
    for (int i = tid; i < 50000; i += 16384) {
        unsigned int w = mw[i];
        if ((w & 0xFFFFu) == 0x3F80u) lowp = 1;
        else if (w == 0x3F800000u) f32w = 1;
        else if (w > 1u) gt1 = 1;
    }
    if (insane) atomicAdd(&cnts[0], insane);
    if (lowp)   atomicOr(&cnts[1], 1);
    if (f32w)   atomicOr(&cnts[2], 1);
    if (gt1)    atomicOr(&cnts[3], 1);
}

__device__ inline bf16 ld_any(const void* p, int i, int f32mode) {
    if (f32mode) return (bf16)((const float*)p)[i];
    return ((const bf16*)p)[i];
}

// convert all float inputs to canonical bf16; w1/w2 written in per-lane
// B-fragment order:
//   Wf[((nt*2+c)*64 + lane)*8 + j] = W[(c*32+(lane>>4)*8+j)*64 + nt*16+(lane&15)]
__global__ void convert_kernel(const int* __restrict__ cnts,
                               const void* x, const void* w1, const void* b1,
                               const void* g1, const void* bb1, const void* w2,
                               const void* b2, const void* g2, const void* bb2,
                               const void* fw, const void* fb,
                               bf16* __restrict__ xb, bf16* __restrict__ params) {
    int t = blockIdx.x * 256 + threadIdx.x;
    if (t >= CVT_TOT) return;
    int f = cnts[0] > 64;
    if (t < 1280000) { xb[t] = ld_any(x, t, f); return; }
    int u = t - 1280000;
    if (u < PB1 || (u >= PW2 && u < PB2)) {       // swizzled weight regions
        const void* src = (u < PB1) ? w1 : w2;
        int v = (u < PB1) ? u : u - PW2;
        int layer = v >> 12, rem = v & 4095;
        int j = rem & 7, lane = (rem >> 3) & 63, ntc = rem >> 9;
        int nt = ntc >> 1, c = ntc & 1;
        int k = c * 32 + (lane >> 4) * 8 + j;
        int n = nt * 16 + (lane & 15);
        params[u] = ld_any(src, layer * 4096 + k * 64 + n, f);
        return;
    }
    const void* src; int base;
    if      (u < PG1)  { src = b1;  base = PB1; }
    else if (u < PBB1) { src = g1;  base = PG1; }
    else if (u < PW2)  { src = bb1; base = PBB1; }
    else if (u < PG2)  { src = b2;  base = PB2; }
    else if (u < PBB2) { src = g2;  base = PG2; }
    else if (u < PFW)  { src = bb2; base = PBB2; }
    else if (u < PFB)  { src = fw;  base = PFW; }
    else               { src = fb;  base = PFB; }
    params[u] = ld_any(src, u - base, f);
}

// h0[(n*10+r)*64+f] = drop[r][n] ? 0 : x[n,f]
__global__ void build_h0_kernel(const bf16* __restrict__ xb, const void* __restrict__ maskp,
                                const int* __restrict__ cnts, bf16* __restrict__ h) {
    int i = blockIdx.x * 256 + threadIdx.x;   // (n*10+r)*8 + c ; 1.6M total
    int c = i & 7;
    int rowid = i >> 3;
    int r = rowid % R_RUNS;
    int n = rowid / R_RUNS;
    size_t midx = (size_t)r * N_NODES + n;
    int w = cnts[1] ? 2 : (cnts[2] ? 4 : (cnts[3] ? 1 : 4));
    int dropped;
    if (w == 1)      dropped = ((const unsigned char*)maskp)[midx] != 0;
    else if (w == 2) dropped = ((const unsigned short*)maskp)[midx] != 0;
    else             dropped = ((const unsigned int*)maskp)[midx] != 0;
    bf16x8 v;
    if (dropped) {
        #pragma unroll
        for (int j = 0; j < 8; ++j) v[j] = (bf16)0.0f;
    } else {
        v = *(const bf16x8*)(xb + (size_t)n * HID + c * 8);
    }
    *(bf16x8*)(h + (size_t)rowid * HID + c * 8) = v;
}

// ---------------- CSR build (keyed by dst) ----------------
__global__ void csr_count_kernel(const int* __restrict__ ei, int* __restrict__ deg) {
    int e = blockIdx.x * 256 + threadIdx.x;
    if (e < N_EDGES) atomicAdd(&deg[ei[N_EDGES + e]], 1);
}

__global__ void csr_scan_kernel(int* __restrict__ deg, int* __restrict__ row_start) {
    __shared__ int lds[1024];
    int tid = threadIdx.x;
    const int CH = 20;
    int base = tid * CH;
    int local[CH];
    int s = 0;
    #pragma unroll
    for (int j = 0; j < CH; ++j) {
        int n = base + j;
        int d = (n < N_NODES) ? deg[n] : 0;
        local[j] = d; s += d;
    }
    lds[tid] = s; __syncthreads();
    for (int off = 1; off < 1024; off <<= 1) {
        int add = (tid >= off) ? lds[tid - off] : 0;
        __syncthreads();
        lds[tid] += add;
        __syncthreads();
    }
    int excl = lds[tid] - s;
    #pragma unroll
    for (int j = 0; j < CH; ++j) {
        int n = base + j;
        if (n < N_NODES) { row_start[n] = excl; deg[n] = excl; excl += local[j]; }
    }
    if (tid == 1023) row_start[N_NODES] = lds[1023];
}

__global__ void csr_fill_kernel(const int* __restrict__ ei, int* __restrict__ cursor,
                                int* __restrict__ col) {
    int e = blockIdx.x * 256 + threadIdx.x;
    if (e < N_EDGES) {
        int src = ei[e];
        int dst = ei[N_EDGES + e];
        int pos = atomicAdd(&cursor[dst], 1);
        col[pos] = src;
    }
}

// ---------------- aggregation: one wave per node, all 10 runs, 4-wide unroll
__global__ __launch_bounds__(256) void agg_kernel(const uint32* __restrict__ hD,
                                                  const int* __restrict__ row_start,
                                                  const int* __restrict__ col,
                                                  uint32* __restrict__ zD) {
    int lane = threadIdx.x & 63;
    int n = blockIdx.x * 4 + (threadIdx.x >> 6);
    const int NODE_DW = R_RUNS * HID / 2;   // 320
    size_t base = (size_t)n * NODE_DW + lane;
    float2 acc[5];
    #pragma unroll
    for (int c = 0; c < 5; ++c) {
        uint32 u = hD[base + c * 64];
        acc[c].x = __uint_as_float(u << 16);
        acc[c].y = __uint_as_float(u & 0xFFFF0000u);
    }
    int beg = row_start[n], end = row_start[n + 1];
    int idx = beg;
    for (; idx + 4 <= end; idx += 4) {
        size_t b0 = (size_t)col[idx]     * NODE_DW + lane;
        size_t b1 = (size_t)col[idx + 1] * NODE_DW + lane;
        size_t b2 = (size_t)col[idx + 2] * NODE_DW + lane;
        size_t b3 = (size_t)col[idx + 3] * NODE_DW + lane;
        uint32 u0[5], u1[5], u2[5], u3[5];
        #pragma unroll
        for (int c = 0; c < 5; ++c) u0[c] = hD[b0 + c * 64];
        #pragma unroll
        for (int c = 0; c < 5; ++c) u1[c] = hD[b1 + c * 64];
        #pragma unroll
        for (int c = 0; c < 5; ++c) u2[c] = hD[b2 + c * 64];
        #pragma unroll
        for (int c = 0; c < 5; ++c) u3[c] = hD[b3 + c * 64];
        #pragma unroll
        for (int c = 0; c < 5; ++c) {
            acc[c].x += __uint_as_float(u0[c] << 16) + __uint_as_float(u1[c] << 16)
                      + __uint_as_float(u2[c] << 16) + __uint_as_float(u3[c] << 16);
            acc[c].y += __uint_as_float(u0[c] & 0xFFFF0000u) + __uint_as_float(u1[c] & 0xFFFF0000u)
                      + __uint_as_float(u2[c] & 0xFFFF0000u) + __uint_as_float(u3[c] & 0xFFFF0000u);
        }
    }
    for (; idx < end; ++idx) {
        size_t b0 = (size_t)col[idx] * NODE_DW + lane;
        #pragma unroll
        for (int c = 0; c < 5; ++c) {
            uint32 u = hD[b0 + c * 64];
            acc[c].x += __uint_as_float(u << 16);
            acc[c].y += __uint_as_float(u & 0xFFFF0000u);
        }
    }
    #pragma unroll
    for (int c = 0; c < 5; ++c) {
        unsigned short lo = __builtin_bit_cast(unsigned short, (bf16)acc[c].x);
        unsigned short hi = __builtin_bit_cast(unsigned short, (bf16)acc[c].y);
        zD[base + c * 64] = (uint32)lo | ((uint32)hi << 16);
    }
}

// ---------------- fused GEMM: out = [bn_relu?](in) @ W + bias, + output stats.
// If statsIn != null: reduce 16-copy raw stats of previous gemm -> scale/shift,
// apply BN+ReLU to input fragments in-register.
// Epilogue: per-wave LDS repack (stride 72, conflict-benign) -> 2x dwordx4
// stores of 1024B contiguous per instruction (was 16x 2B stores/thread).
// in/out may alias (per-wave 16-row slice; loads complete before stores).
__global__ __launch_bounds__(256) void gemm64_kernel(const bf16* in,
                                                     const bf16* __restrict__ Wf,
                                                     const bf16* __restrict__ bias,
                                                     bf16* out,
                                                     const float* __restrict__ statsIn,
                                                     const bf16* __restrict__ gammaIn,
                                                     const bf16* __restrict__ betaIn,
                                                     float* __restrict__ statsOut) {
    __shared__ float lstat[128];
    __shared__ float lscale[64], lshift[64];
    __shared__ float lsum[64], lsq[64];
    __shared__ __align__(16) bf16 lC[4][16][72];
    int tid = threadIdx.x;
    int wave = tid >> 6, lane = tid & 63, l16 = lane & 15, quad = lane >> 4;

    if (statsIn) {
        if (tid < 128) {
            float s = 0.f;
            #pragma unroll
            for (int k = 0; k < NCOPY; ++k) s += statsIn[k * 128 + tid];
            lstat[tid] = s;
        }
    }
    if (tid < 64) { lsum[tid] = 0.f; lsq[tid] = 0.f; }
    __syncthreads();
    if (statsIn && tid < 64) {
        float mu = lstat[tid] * (1.0f / MROWS);
        float var = lstat[tid + 64] * (1.0f / MROWS) - mu * mu;
        float rs = rsqrtf(var + BN_EPS);
        float a = (float)gammaIn[tid] * rs;
        lscale[tid] = a;
        lshift[tid] = (float)betaIn[tid] - mu * a;
    }
    if (statsIn) __syncthreads();

    size_t rowBase = (size_t)blockIdx.x * 64 + wave * 16;

    bf16x8 bfrag[4][2];
    #pragma unroll
    for (int nt = 0; nt < 4; ++nt)
        #pragma unroll
        for (int c = 0; c < 2; ++c)
            bfrag[nt][c] = *(const bf16x8*)(Wf + (size_t)((nt * 2 + c) * 64 + lane) * 8);

    f32x4 acc[4];
    #pragma unroll
    for (int nt = 0; nt < 4; ++nt) {
        float bv = (float)bias[nt * 16 + l16];
        acc[nt] = (f32x4){bv, bv, bv, bv};
    }

    size_t row = rowBase + l16;
    bf16x8 afrag[2];
    #pragma unroll
    for (int c = 0; c < 2; ++c) {
        int k0 = c * 32 + quad * 8;
        bf16x8 v = *(const bf16x8*)(in + row * HID + k0);
        if (statsIn) {
            #pragma unroll
            for (int j = 0; j < 8; ++j) {
                float f = (float)v[j] * lscale[k0 + j] + lshift[k0 + j];
                v[j] = (bf16)fmaxf(f, 0.f);
            }
        }
        afrag[c] = v;
    }

    #pragma unroll
    for (int nt = 0; nt < 4; ++nt) {
        acc[nt] = __builtin_amdgcn_mfma_f32_16x16x32_bf16(afrag[0], bfrag[nt][0], acc[nt], 0, 0, 0);
        acc[nt] = __builtin_amdgcn_mfma_f32_16x16x32_bf16(afrag[1], bfrag[nt][1], acc[nt], 0, 0, 0);
    }

    // epilogue: wave-local LDS repack (no barrier needed; DS ops in-order per wave)
    #pragma unroll
    for (int nt = 0; nt < 4; ++nt)
        #pragma unroll
        for (int reg = 0; reg < 4; ++reg)
            lC[wave][quad * 4 + reg][nt * 16 + l16] = (bf16)acc[nt][reg];

    #pragma unroll
    for (int p = 0; p < 2; ++p) {
        int r = p * 8 + (lane >> 3);
        int sg = lane & 7;
        bf16x8 v = *(const bf16x8*)&lC[wave][r][sg * 8];
        *(bf16x8*)(out + (rowBase + r) * HID + sg * 8) = v;
    }

    // column stats of pre-BN output from fp32 accumulators
    #pragma unroll
    for (int nt = 0; nt < 4; ++nt) {
        float s = 0.f, q = 0.f;
        #pragma unroll
        for (int reg = 0; reg < 4; ++reg) { float v = acc[nt][reg]; s += v; q += v * v; }
        atomicAdd(&lsum[nt * 16 + l16], s);
        atomicAdd(&lsq[nt * 16 + l16], q);
    }
    __syncthreads();
    if (tid < 64) {
        int copy = blockIdx.x & (NCOPY - 1);
        atomicAdd(&statsOut[copy * 128 + tid], lsum[tid]);
        atomicAdd(&statsOut[copy * 128 + 64 + tid], lsq[tid]);
    }
}

// fused stats reduce + BN+ReLU + h-materialize + pool; dword-granular.
// Thread owns feature PAIR fd of node n (gid = n*32+fd). statsIn==null:
// level-0 raw pool (no BN, no hOut write).
__global__ __launch_bounds__(256) void pool_bn_kernel(const uint32* __restrict__ tD,
                                                      const float* __restrict__ statsIn,
                                                      const bf16* __restrict__ gammaIn,
                                                      const bf16* __restrict__ betaIn,
                                                      uint32* __restrict__ hD,
                                                      const int* __restrict__ batch,
                                                      float* __restrict__ pooled) {
    __shared__ float lstat[128], lscale[64], lshift[64];
    int tid = threadIdx.x;
    if (statsIn) {
        if (tid < 128) {
            float s = 0.f;
            #pragma unroll
            for (int k = 0; k < NCOPY; ++k) s += statsIn[k * 128 + tid];
            lstat[tid] = s;
        }
        __syncthreads();
        if (tid < 64) {
            float mu = lstat[tid] * (1.0f / MROWS);
            float var = lstat[tid + 64] * (1.0f / MROWS) - mu * mu;
            float rs = rsqrtf(var + BN_EPS);
            float a = (float)gammaIn[tid] * rs;
            lscale[tid] = a;
            lshift[tid] = (float)betaIn[tid] - mu * a;
        }
        __syncthreads();
    }
    int gid = blockIdx.x * 256 + tid;   // n*32 + fd ; 640000 total
    int fd = gid & 31, n = gid >> 5;
    float sc0 = statsIn ? lscale[2 * fd] : 1.f;
    float sc1 = statsIn ? lscale[2 * fd + 1] : 1.f;
    float sh0 = statsIn ? lshift[2 * fd] : 0.f;
    float sh1 = statsIn ? lshift[2 * fd + 1] : 0.f;
    size_t base = (size_t)n * (R_RUNS * HID / 2) + fd;
    float s0 = 0.f, s1 = 0.f;
    #pragma unroll
    for (int r = 0; r < R_RUNS; ++r) {
        uint32 u = tD[base + r * 32];
        float v0 = __uint_as_float(u << 16);
        float v1 = __uint_as_float(u & 0xFFFF0000u);
        if (statsIn) {
            v0 = fmaxf(v0 * sc0 + sh0, 0.f);
            v1 = fmaxf(v1 * sc1 + sh1, 0.f);
            unsigned short lo = __builtin_bit_cast(unsigned short, (bf16)v0);
            unsigned short hi = __builtin_bit_cast(unsigned short, (bf16)v1);
            hD[base + r * 32] = (uint32)lo | ((uint32)hi << 16);
        }
        s0 += v0; s1 += v1;
    }
    int g = batch[n];
    atomicAdd(&pooled[g * HID + 2 * fd],     s0 * (1.0f / R_RUNS));
    atomicAdd(&pooled[g * HID + 2 * fd + 1], s1 * (1.0f / R_RUNS));
}

// final: out[g,:] = log_softmax( sum_l pooled5[l][g] @ fcw_l + fcb_l )
__global__ void fc_softmax_kernel(const float* __restrict__ pooled5,
                                  const bf16* __restrict__ params,
                                  const int* __restrict__ cnts, void* __restrict__ out) {
    int g = threadIdx.x;   // 128 threads
    if (g >= NG) return;
    float o[NC];
    #pragma unroll
    for (int c = 0; c < NC; ++c) o[c] = 0.f;
    for (int l = 0; l < NL + 1; ++l) {
        const float* pg = pooled5 + ((size_t)l * NG + g) * HID;
        const bf16* fw = params + PFW + l * (HID * NC);
        for (int k = 0; k < HID; ++k) {
            float p = pg[k];
            #pragma unroll
            for (int c = 0; c < NC; ++c) o[c] += p * (float)fw[k * NC + c];
        }
        #pragma unroll
        for (int c = 0; c < NC; ++c) o[c] += (float)params[PFB + l * NC + c];
    }
    float m = -1e30f;
    #pragma unroll
    for (int c = 0; c < NC; ++c) m = fmaxf(m, o[c]);
    float s = 0.f;
    #pragma unroll
    for (int c = 0; c < NC; ++c) s += expf(o[c] - m);
    float lg = logf(s);
    int f = cnts[0] > 64;
    #pragma unroll
    for (int c = 0; c < NC; ++c) {
        float val = o[c] - m - lg;
        if (f) ((float*)out)[g * NC + c] = val;
        else   ((bf16*)out)[g * NC + c] = (bf16)val;
    }
}

extern "C" void kernel_launch(void* const* d_in, const int* in_sizes, int n_in,
                              void* d_out, int out_size, void* d_ws, size_t ws_size,
                              hipStream_t stream) {
    const void* x     = d_in[0];
    const int*  ei    = (const int*)d_in[1];
    const int*  batch = (const int*)d_in[2];
    const void* maskp = d_in[3];

    char* ws = (char*)d_ws;
    int*   cnts    = (int*)(ws + OFF_FLAGS);
    int*   cursor  = (int*)(ws + OFF_CURSOR);
    float* statsb  = (float*)(ws + OFF_STATS);
    float* pooled5 = (float*)(ws + OFF_POOLED5);
    int*   rowst   = (int*)(ws + OFF_ROWST);
    int*   colbuf  = (int*)(ws + OFF_COL);
    bf16*  params  = (bf16*)(ws + OFF_PARAMS);
    bf16*  xb      = (bf16*)(ws + OFF_XB);
    bf16*  h       = (bf16*)(ws + OFF_H);
    bf16*  z       = (bf16*)(ws + OFF_Z);

    hipMemsetAsync(ws, 0, ZERO_BYTES, stream);   // flags+cursor+stats+pooled5

    detect_kernel<<<64, 256, 0, stream>>>((const unsigned short*)x,
                                          (const unsigned int*)maskp, cnts);
    convert_kernel<<<(CVT_TOT + 255) / 256, 256, 0, stream>>>(
        cnts, x, d_in[4], d_in[5], d_in[6], d_in[7], d_in[8], d_in[9], d_in[10],
        d_in[11], d_in[12], d_in[13], xb, params);

    build_h0_kernel<<<(MROWS * 8) / 256, 256, 0, stream>>>(xb, maskp, cnts, h);

    csr_count_kernel<<<(N_EDGES + 255) / 256, 256, 0, stream>>>(ei, cursor);
    csr_scan_kernel<<<1, 1024, 0, stream>>>(cursor, rowst);
    csr_fill_kernel<<<(N_EDGES + 255) / 256, 256, 0, stream>>>(ei, cursor, colbuf);

    // level 0: raw pool of h0
    pool_bn_kernel<<<(N_NODES * 32) / 256, 256, 0, stream>>>(
        (const uint32*)h, nullptr, nullptr, nullptr, nullptr, batch, pooled5);

    for (int i = 0; i < NL; ++i) {
        float* st1 = statsb + (size_t)(2 * i) * (NCOPY * 128);
        float* st2 = statsb + (size_t)(2 * i + 1) * (NCOPY * 128);

        agg_kernel<<<N_NODES / 4, 256, 0, stream>>>((const uint32*)h, rowst, colbuf,
                                                    (uint32*)z);

        gemm64_kernel<<<MROWS / 64, 256, 0, stream>>>(
            z, params + PW1 + i * 4096, params + PB1 + i * 64, z,
            nullptr, nullptr, nullptr, st1);

        gemm64_kernel<<<MROWS / 64, 256, 0, stream>>>(
            z, params + PW2 + i * 4096, params + PB2 + i * 64, z,
            st1, params + PG1 + i * 64, params + PBB1 + i * 64, st2);

        pool_bn_kernel<<<(N_NODES * 32) / 256, 256, 0, stream>>>(
            (const uint32*)z, st2, params + PG2 + i * 64, params + PBB2 + i * 64,
            (uint32*)h, batch, pooled5 + (size_t)(i + 1) * NG * HID);
    }

    fc_softmax_kernel<<<1, 128, 0, stream>>>(pooled5, params, cnts, d_out);
}

// Round 7
// 868.954 us; speedup vs baseline: 1.1082x; 1.1082x over previous
//
#include <hip/hip_runtime.h>

#define N_NODES 20000
#define N_EDGES 320000
#define R_RUNS 10
#define HID 64
#define NG 128
#define NC 10
#define NL 4
#define MROWS (R_RUNS * N_NODES)   // 200000
#define BN_EPS 1e-5f
#define NCOPY 16                   // stats copies per buffer

typedef __bf16 bf16;
typedef __attribute__((ext_vector_type(8))) __bf16 bf16x8;
typedef __attribute__((ext_vector_type(4))) float f32x4;
typedef unsigned int uint32;

// ---------------- workspace layout (bytes)
// Feature layout [n][r][f] (row = n*10+r): agg gathers a neighbor's 10 runs
// from one contiguous 1280B span; pool's r-reduction is contiguous.
constexpr size_t OFF_FLAGS   = 0;          // int[4] counters, pad 256
constexpr size_t OFF_CURSOR  = 256;        // int[20001] -> pad 80384
constexpr size_t OFF_STATS   = 80384;      // f32[8 bufs][16 copies][128] = 65536
constexpr size_t OFF_POOLED5 = 145920;     // f32[5][128][64] = 163840
constexpr size_t ZERO_BYTES  = 309760;
constexpr size_t OFF_ROWST   = 309760;     // int[20001] -> pad 389888
constexpr size_t OFF_COL     = 389888;     // int[320000] -> 1669888
constexpr size_t OFF_PARAMS  = 1669888;    // bf16[37554] -> pad 1745152
constexpr size_t OFF_XB      = 1745152;    // bf16[1280000] -> 4305152
constexpr size_t OFF_H       = 4305152;    // 25,600,000
constexpr size_t OFF_Z       = 29905152;   // 25,600,000 -> end 55,505,152

// params block element offsets (w1/w2 stored PRE-SWIZZLED in B-fragment order)
#define PW1  0
#define PB1  16384
#define PG1  16640
#define PBB1 16896
#define PW2  17152
#define PB2  33536
#define PG2  33792
#define PBB2 34048
#define PFW  34304
#define PFB  37504
#define PTOT 37554
#define CVT_TOT (1280000 + PTOT)

// ---------------- runtime dtype detection (validated R4/R5) ----------------
__global__ void detect_kernel(const unsigned short* __restrict__ xu,
                              const unsigned int* __restrict__ mw,
                              int* __restrict__ cnts) {
    int tid = blockIdx.x * 256 + threadIdx.x;   // 16384 threads
    int insane = 0, lowp = 0, f32w = 0, gt1 = 0;
    for (int i = tid; i < 4096; i += 16384) {
        unsigned int u = xu[2 * i];
        if (((u >> 7) & 0xFFu) >= 0x90u) insane++;
    }
    for (int i = tid; i < 50000; i += 16384) {
        unsigned int w = mw[i];
        if ((w & 0xFFFFu) == 0x3F80u) lowp = 1;
        else if (w == 0x3F800000u) f32w = 1;
        else if (w > 1u) gt1 = 1;
    }
    if (insane) atomicAdd(&cnts[0], insane);
    if (lowp)   atomicOr(&cnts[1], 1);
    if (f32w)   atomicOr(&cnts[2], 1);
    if (gt1)    atomicOr(&cnts[3], 1);
}

__device__ inline bf16 ld_any(const void* p, int i, int f32mode) {
    if (f32mode) return (bf16)((const float*)p)[i];
    return ((const bf16*)p)[i];
}

// convert all float inputs to canonical bf16; w1/w2 written in per-lane
// B-fragment order:
//   Wf[((nt*2+c)*64 + lane)*8 + j] = W[(c*32+(lane>>4)*8+j)*64 + nt*16+(lane&15)]
__global__ void convert_kernel(const int* __restrict__ cnts,
                               const void* x, const void* w1, const void* b1,
                               const void* g1, const void* bb1, const void* w2,
                               const void* b2, const void* g2, const void* bb2,
                               const void* fw, const void* fb,
                               bf16* __restrict__ xb, bf16* __restrict__ params) {
    int t = blockIdx.x * 256 + threadIdx.x;
    if (t >= CVT_TOT) return;
    int f = cnts[0] > 64;
    if (t < 1280000) { xb[t] = ld_any(x, t, f); return; }
    int u = t - 1280000;
    if (u < PB1 || (u >= PW2 && u < PB2)) {       // swizzled weight regions
        const void* src = (u < PB1) ? w1 : w2;
        int v = (u < PB1) ? u : u - PW2;
        int layer = v >> 12, rem = v & 4095;
        int j = rem & 7, lane = (rem >> 3) & 63, ntc = rem >> 9;
        int nt = ntc >> 1, c = ntc & 1;
        int k = c * 32 + (lane >> 4) * 8 + j;
        int n = nt * 16 + (lane & 15);
        params[u] = ld_any(src, layer * 4096 + k * 64 + n, f);
        return;
    }
    const void* src; int base;
    if      (u < PG1)  { src = b1;  base = PB1; }
    else if (u < PBB1) { src = g1;  base = PG1; }
    else if (u < PW2)  { src = bb1; base = PBB1; }
    else if (u < PG2)  { src = b2;  base = PB2; }
    else if (u < PBB2) { src = g2;  base = PG2; }
    else if (u < PFW)  { src = bb2; base = PBB2; }
    else if (u < PFB)  { src = fw;  base = PFW; }
    else               { src = fb;  base = PFB; }
    params[u] = ld_any(src, u - base, f);
}

// h0[(n*10+r)*64+f] = drop[r][n] ? 0 : x[n,f]
__global__ void build_h0_kernel(const bf16* __restrict__ xb, const void* __restrict__ maskp,
                                const int* __restrict__ cnts, bf16* __restrict__ h) {
    int i = blockIdx.x * 256 + threadIdx.x;   // (n*10+r)*8 + c ; 1.6M total
    int c = i & 7;
    int rowid = i >> 3;
    int r = rowid % R_RUNS;
    int n = rowid / R_RUNS;
    size_t midx = (size_t)r * N_NODES + n;
    int w = cnts[1] ? 2 : (cnts[2] ? 4 : (cnts[3] ? 1 : 4));
    int dropped;
    if (w == 1)      dropped = ((const unsigned char*)maskp)[midx] != 0;
    else if (w == 2) dropped = ((const unsigned short*)maskp)[midx] != 0;
    else             dropped = ((const unsigned int*)maskp)[midx] != 0;
    bf16x8 v;
    if (dropped) {
        #pragma unroll
        for (int j = 0; j < 8; ++j) v[j] = (bf16)0.0f;
    } else {
        v = *(const bf16x8*)(xb + (size_t)n * HID + c * 8);
    }
    *(bf16x8*)(h + (size_t)rowid * HID + c * 8) = v;
}

// ---------------- CSR build (keyed by dst) ----------------
__global__ void csr_count_kernel(const int* __restrict__ ei, int* __restrict__ deg) {
    int e = blockIdx.x * 256 + threadIdx.x;
    if (e < N_EDGES) atomicAdd(&deg[ei[N_EDGES + e]], 1);
}

__global__ void csr_scan_kernel(int* __restrict__ deg, int* __restrict__ row_start) {
    __shared__ int lds[1024];
    int tid = threadIdx.x;
    const int CH = 20;
    int base = tid * CH;
    int local[CH];
    int s = 0;
    #pragma unroll
    for (int j = 0; j < CH; ++j) {
        int n = base + j;
        int d = (n < N_NODES) ? deg[n] : 0;
        local[j] = d; s += d;
    }
    lds[tid] = s; __syncthreads();
    for (int off = 1; off < 1024; off <<= 1) {
        int add = (tid >= off) ? lds[tid - off] : 0;
        __syncthreads();
        lds[tid] += add;
        __syncthreads();
    }
    int excl = lds[tid] - s;
    #pragma unroll
    for (int j = 0; j < CH; ++j) {
        int n = base + j;
        if (n < N_NODES) { row_start[n] = excl; deg[n] = excl; excl += local[j]; }
    }
    if (tid == 1023) row_start[N_NODES] = lds[1023];
}

__global__ void csr_fill_kernel(const int* __restrict__ ei, int* __restrict__ cursor,
                                int* __restrict__ col) {
    int e = blockIdx.x * 256 + threadIdx.x;
    if (e < N_EDGES) {
        int src = ei[e];
        int dst = ei[N_EDGES + e];
        int pos = atomicAdd(&cursor[dst], 1);
        col[pos] = src;
    }
}

// ---------------- aggregation: one wave per node, all 10 runs.
// Node span = 1280B. Lane covers 20B: uint4 at dword 4*lane (bytes 0..1023)
// + tail dword at 256+lane (bytes 1024..1279). 2 VMEM instr per neighbor
// (was 5) — tests whether agg is request-rate- or BW-limited.
__global__ __launch_bounds__(256) void agg_kernel(const uint32* __restrict__ hD,
                                                  const int* __restrict__ row_start,
                                                  const int* __restrict__ col,
                                                  uint32* __restrict__ zD) {
    int lane = threadIdx.x & 63;
    int n = blockIdx.x * 4 + (threadIdx.x >> 6);
    const int NODE_DW = R_RUNS * HID / 2;   // 320
    size_t base4 = (size_t)n * NODE_DW + lane * 4;
    size_t baset = (size_t)n * NODE_DW + 256 + lane;
    float acc[10];
    {
        uint4 u = *(const uint4*)(hD + base4);
        uint32 t = hD[baset];
        acc[0] = __uint_as_float(u.x << 16); acc[1] = __uint_as_float(u.x & 0xFFFF0000u);
        acc[2] = __uint_as_float(u.y << 16); acc[3] = __uint_as_float(u.y & 0xFFFF0000u);
        acc[4] = __uint_as_float(u.z << 16); acc[5] = __uint_as_float(u.z & 0xFFFF0000u);
        acc[6] = __uint_as_float(u.w << 16); acc[7] = __uint_as_float(u.w & 0xFFFF0000u);
        acc[8] = __uint_as_float(t << 16);   acc[9] = __uint_as_float(t & 0xFFFF0000u);
    }
    int beg = row_start[n], end = row_start[n + 1];
    int idx = beg;
    for (; idx + 4 <= end; idx += 4) {
        int s0 = col[idx], s1 = col[idx + 1], s2 = col[idx + 2], s3 = col[idx + 3];
        size_t o0 = (size_t)s0 * NODE_DW, o1 = (size_t)s1 * NODE_DW;
        size_t o2 = (size_t)s2 * NODE_DW, o3 = (size_t)s3 * NODE_DW;
        uint4 a0 = *(const uint4*)(hD + o0 + lane * 4);
        uint4 a1 = *(const uint4*)(hD + o1 + lane * 4);
        uint4 a2 = *(const uint4*)(hD + o2 + lane * 4);
        uint4 a3 = *(const uint4*)(hD + o3 + lane * 4);
        uint32 t0 = hD[o0 + 256 + lane];
        uint32 t1 = hD[o1 + 256 + lane];
        uint32 t2 = hD[o2 + 256 + lane];
        uint32 t3 = hD[o3 + 256 + lane];
        uint32 w0[4] = {a0.x, a0.y, a0.z, a0.w};
        uint32 w1[4] = {a1.x, a1.y, a1.z, a1.w};
        uint32 w2[4] = {a2.x, a2.y, a2.z, a2.w};
        uint32 w3[4] = {a3.x, a3.y, a3.z, a3.w};
        #pragma unroll
        for (int c = 0; c < 4; ++c) {
            acc[2 * c]     += __uint_as_float(w0[c] << 16) + __uint_as_float(w1[c] << 16)
                            + __uint_as_float(w2[c] << 16) + __uint_as_float(w3[c] << 16);
            acc[2 * c + 1] += __uint_as_float(w0[c] & 0xFFFF0000u) + __uint_as_float(w1[c] & 0xFFFF0000u)
                            + __uint_as_float(w2[c] & 0xFFFF0000u) + __uint_as_float(w3[c] & 0xFFFF0000u);
        }
        acc[8] += __uint_as_float(t0 << 16) + __uint_as_float(t1 << 16)
                + __uint_as_float(t2 << 16) + __uint_as_float(t3 << 16);
        acc[9] += __uint_as_float(t0 & 0xFFFF0000u) + __uint_as_float(t1 & 0xFFFF0000u)
                + __uint_as_float(t2 & 0xFFFF0000u) + __uint_as_float(t3 & 0xFFFF0000u);
    }
    for (; idx < end; ++idx) {
        size_t o0 = (size_t)col[idx] * NODE_DW;
        uint4 a0 = *(const uint4*)(hD + o0 + lane * 4);
        uint32 t0 = hD[o0 + 256 + lane];
        uint32 w0[4] = {a0.x, a0.y, a0.z, a0.w};
        #pragma unroll
        for (int c = 0; c < 4; ++c) {
            acc[2 * c]     += __uint_as_float(w0[c] << 16);
            acc[2 * c + 1] += __uint_as_float(w0[c] & 0xFFFF0000u);
        }
        acc[8] += __uint_as_float(t0 << 16);
        acc[9] += __uint_as_float(t0 & 0xFFFF0000u);
    }
    uint4 o;
    uint32 ot;
    {
        uint32 p[5];
        #pragma unroll
        for (int c = 0; c < 5; ++c) {
            unsigned short lo = __builtin_bit_cast(unsigned short, (bf16)acc[2 * c]);
            unsigned short hi = __builtin_bit_cast(unsigned short, (bf16)acc[2 * c + 1]);
            p[c] = (uint32)lo | ((uint32)hi << 16);
        }
        o.x = p[0]; o.y = p[1]; o.z = p[2]; o.w = p[3]; ot = p[4];
    }
    *(uint4*)(zD + base4) = o;
    zD[baset] = ot;
}

// ---------------- fused GEMM (R5 form): out = [bn_relu?](in) @ W + bias,
// + output stats. If statsIn != null: reduce 16-copy raw stats of the
// PREVIOUS gemm -> scale/shift, apply BN+ReLU to input frags in-register.
// Wf pre-swizzled. in/out may alias (per-wave 16-row slice; MFMA data dep
// orders loads before stores).
__global__ __launch_bounds__(256) void gemm64_kernel(const bf16* in,
                                                     const bf16* __restrict__ Wf,
                                                     const bf16* __restrict__ bias,
                                                     bf16* out,
                                                     const float* __restrict__ statsIn,
                                                     const bf16* __restrict__ gammaIn,
                                                     const bf16* __restrict__ betaIn,
                                                     float* __restrict__ statsOut) {
    __shared__ float lstat[128];
    __shared__ float lscale[64], lshift[64];
    __shared__ float lsum[64], lsq[64];
    int tid = threadIdx.x;
    int wave = tid >> 6, lane = tid & 63, l16 = lane & 15, quad = lane >> 4;

    if (statsIn) {
        if (tid < 128) {
            float s = 0.f;
            #pragma unroll
            for (int k = 0; k < NCOPY; ++k) s += statsIn[k * 128 + tid];
            lstat[tid] = s;
        }
    }
    if (tid < 64) { lsum[tid] = 0.f; lsq[tid] = 0.f; }
    __syncthreads();
    if (statsIn && tid < 64) {
        float mu = lstat[tid] * (1.0f / MROWS);
        float var = lstat[tid + 64] * (1.0f / MROWS) - mu * mu;
        float rs = rsqrtf(var + BN_EPS);
        float a = (float)gammaIn[tid] * rs;
        lscale[tid] = a;
        lshift[tid] = (float)betaIn[tid] - mu * a;
    }
    if (statsIn) __syncthreads();

    size_t rowBase = (size_t)blockIdx.x * 64 + wave * 16;

    bf16x8 bfrag[4][2];
    #pragma unroll
    for (int nt = 0; nt < 4; ++nt)
        #pragma unroll
        for (int c = 0; c < 2; ++c)
            bfrag[nt][c] = *(const bf16x8*)(Wf + (size_t)((nt * 2 + c) * 64 + lane) * 8);

    f32x4 acc[4];
    #pragma unroll
    for (int nt = 0; nt < 4; ++nt) {
        float bv = (float)bias[nt * 16 + l16];
        acc[nt] = (f32x4){bv, bv, bv, bv};
    }

    size_t row = rowBase + l16;
    bf16x8 afrag[2];
    #pragma unroll
    for (int c = 0; c < 2; ++c) {
        int k0 = c * 32 + quad * 8;
        bf16x8 v = *(const bf16x8*)(in + row * HID + k0);
        if (statsIn) {
            #pragma unroll
            for (int j = 0; j < 8; ++j) {
                float f = (float)v[j] * lscale[k0 + j] + lshift[k0 + j];
                v[j] = (bf16)fmaxf(f, 0.f);
            }
        }
        afrag[c] = v;
    }

    #pragma unroll
    for (int nt = 0; nt < 4; ++nt) {
        acc[nt] = __builtin_amdgcn_mfma_f32_16x16x32_bf16(afrag[0], bfrag[nt][0], acc[nt], 0, 0, 0);
        acc[nt] = __builtin_amdgcn_mfma_f32_16x16x32_bf16(afrag[1], bfrag[nt][1], acc[nt], 0, 0, 0);
    }

    #pragma unroll
    for (int nt = 0; nt < 4; ++nt)
        #pragma unroll
        for (int reg = 0; reg < 4; ++reg) {
            size_t orow = rowBase + quad * 4 + reg;
            out[orow * HID + nt * 16 + l16] = (bf16)acc[nt][reg];
        }

    // column stats of pre-BN output from fp32 accumulators
    #pragma unroll
    for (int nt = 0; nt < 4; ++nt) {
        float s = 0.f, q = 0.f;
        #pragma unroll
        for (int reg = 0; reg < 4; ++reg) { float v = acc[nt][reg]; s += v; q += v * v; }
        atomicAdd(&lsum[nt * 16 + l16], s);
        atomicAdd(&lsq[nt * 16 + l16], q);
    }
    __syncthreads();
    if (tid < 64) {
        int copy = blockIdx.x & (NCOPY - 1);
        atomicAdd(&statsOut[copy * 128 + tid], lsum[tid]);
        atomicAdd(&statsOut[copy * 128 + 64 + tid], lsq[tid]);
    }
}

// fused stats reduce + BN+ReLU + h-materialize + pool (R5 form).
// statsIn==null: level-0 raw pool (no BN, no hOut write).
__global__ __launch_bounds__(256) void pool_bn_kernel(const bf16* __restrict__ t,
                                                      const float* __restrict__ statsIn,
                                                      const bf16* __restrict__ gammaIn,
                                                      const bf16* __restrict__ betaIn,
                                                      bf16* __restrict__ hOut,
                                                      const int* __restrict__ batch,
                                                      float* __restrict__ pooled) {
    __shared__ float lstat[128], lscale[64], lshift[64];
    int tid = threadIdx.x;
    if (statsIn) {
        if (tid < 128) {
            float s = 0.f;
            #pragma unroll
            for (int k = 0; k < NCOPY; ++k) s += statsIn[k * 128 + tid];
            lstat[tid] = s;
        }
        __syncthreads();
        if (tid < 64) {
            float mu = lstat[tid] * (1.0f / MROWS);
            float var = lstat[tid + 64] * (1.0f / MROWS) - mu * mu;
            float rs = rsqrtf(var + BN_EPS);
            float a = (float)gammaIn[tid] * rs;
            lscale[tid] = a;
            lshift[tid] = (float)betaIn[tid] - mu * a;
        }
        __syncthreads();
    }
    int gid = blockIdx.x * 256 + tid;   // n*64+f
    int f = tid & 63, n = gid >> 6;
    float sc = statsIn ? lscale[f] : 1.f;
    float sh = statsIn ? lshift[f] : 0.f;
    size_t base = (size_t)n * (R_RUNS * HID) + f;
    float s = 0.f;
    #pragma unroll
    for (int r = 0; r < R_RUNS; ++r) {
        float v = (float)t[base + r * HID];
        if (statsIn) {
            v = fmaxf(v * sc + sh, 0.f);
            hOut[base + r * HID] = (bf16)v;
        }
        s += v;
    }
    atomicAdd(&pooled[batch[n] * HID + f], s * (1.0f / R_RUNS));
}

// final: out[g,:] = log_softmax( sum_l pooled5[l][g] @ fcw_l + fcb_l )
__global__ void fc_softmax_kernel(const float* __restrict__ pooled5,
                                  const bf16* __restrict__ params,
                                  const int* __restrict__ cnts, void* __restrict__ out) {
    int g = threadIdx.x;   // 128 threads
    if (g >= NG) return;
    float o[NC];
    #pragma unroll
    for (int c = 0; c < NC; ++c) o[c] = 0.f;
    for (int l = 0; l < NL + 1; ++l) {
        const float* pg = pooled5 + ((size_t)l * NG + g) * HID;
        const bf16* fw = params + PFW + l * (HID * NC);
        for (int k = 0; k < HID; ++k) {
            float p = pg[k];
            #pragma unroll
            for (int c = 0; c < NC; ++c) o[c] += p * (float)fw[k * NC + c];
        }
        #pragma unroll
        for (int c = 0; c < NC; ++c) o[c] += (float)params[PFB + l * NC + c];
    }
    float m = -1e30f;
    #pragma unroll
    for (int c = 0; c < NC; ++c) m = fmaxf(m, o[c]);
    float s = 0.f;
    #pragma unroll
    for (int c = 0; c < NC; ++c) s += expf(o[c] - m);
    float lg = logf(s);
    int f = cnts[0] > 64;
    #pragma unroll
    for (int c = 0; c < NC; ++c) {
        float val = o[c] - m - lg;
        if (f) ((float*)out)[g * NC + c] = val;
        else   ((bf16*)out)[g * NC + c] = (bf16)val;
    }
}

extern "C" void kernel_launch(void* const* d_in, const int* in_sizes, int n_in,
                              void* d_out, int out_size, void* d_ws, size_t ws_size,
                              hipStream_t stream) {
    const void* x     = d_in[0];
    const int*  ei    = (const int*)d_in[1];
    const int*  batch = (const int*)d_in[2];
    const void* maskp = d_in[3];

    char* ws = (char*)d_ws;
    int*   cnts    = (int*)(ws + OFF_FLAGS);
    int*   cursor  = (int*)(ws + OFF_CURSOR);
    float* statsb  = (float*)(ws + OFF_STATS);
    float* pooled5 = (float*)(ws + OFF_POOLED5);
    int*   rowst   = (int*)(ws + OFF_ROWST);
    int*   colbuf  = (int*)(ws + OFF_COL);
    bf16*  params  = (bf16*)(ws + OFF_PARAMS);
    bf16*  xb      = (bf16*)(ws + OFF_XB);
    bf16*  h       = (bf16*)(ws + OFF_H);
    bf16*  z       = (bf16*)(ws + OFF_Z);

    hipMemsetAsync(ws, 0, ZERO_BYTES, stream);   // flags+cursor+stats+pooled5

    detect_kernel<<<64, 256, 0, stream>>>((const unsigned short*)x,
                                          (const unsigned int*)maskp, cnts);
    convert_kernel<<<(CVT_TOT + 255) / 256, 256, 0, stream>>>(
        cnts, x, d_in[4], d_in[5], d_in[6], d_in[7], d_in[8], d_in[9], d_in[10],
        d_in[11], d_in[12], d_in[13], xb, params);

    build_h0_kernel<<<(MROWS * 8) / 256, 256, 0, stream>>>(xb, maskp, cnts, h);

    csr_count_kernel<<<(N_EDGES + 255) / 256, 256, 0, stream>>>(ei, cursor);
    csr_scan_kernel<<<1, 1024, 0, stream>>>(cursor, rowst);
    csr_fill_kernel<<<(N_EDGES + 255) / 256, 256, 0, stream>>>(ei, cursor, colbuf);

    // level 0: raw pool of h0
    pool_bn_kernel<<<(N_NODES * HID) / 256, 256, 0, stream>>>(
        h, nullptr, nullptr, nullptr, nullptr, batch, pooled5);

    for (int i = 0; i < NL; ++i) {
        float* st1 = statsb + (size_t)(2 * i) * (NCOPY * 128);
        float* st2 = statsb + (size_t)(2 * i + 1) * (NCOPY * 128);

        agg_kernel<<<N_NODES / 4, 256, 0, stream>>>((const uint32*)h, rowst, colbuf,
                                                    (uint32*)z);

        gemm64_kernel<<<MROWS / 64, 256, 0, stream>>>(
            z, params + PW1 + i * 4096, params + PB1 + i * 64, z,
            nullptr, nullptr, nullptr, st1);

        gemm64_kernel<<<MROWS / 64, 256, 0, stream>>>(
            z, params + PW2 + i * 4096, params + PB2 + i * 64, z,
            st1, params + PG1 + i * 64, params + PBB1 + i * 64, st2);

        pool_bn_kernel<<<(N_NODES * HID) / 256, 256, 0, stream>>>(
            z, st2, params + PG2 + i * 64, params + PBB2 + i * 64, h, batch,
            pooled5 + (size_t)(i + 1) * NG * HID);
    }

    fc_softmax_kernel<<<1, 128, 0, stream>>>(pooled5, params, cnts, d_out);
}